// Round 17
// baseline (58.870 us; speedup 1.0000x reference)
//
#include <hip/hip_runtime.h>

#define EPS 1e-3f
#define Bn 16
#define Tn 2048
#define Dn 256
#define Kn 8

#define TS2 32           // t-chunks per batch row for pass2
#define TCH2 (Tn / TS2)  // 64

#define KBD ((size_t)Kn * Bn * Dn)   // 32768  (= [kk][b][d][2] paired layout)
#define KD  (Kn * Dn)                // 2048   (= [kk][d][2])

typedef float v2f __attribute__((ext_vector_type(2)));

__device__ __forceinline__ float fexp2(float x) {
#if __has_builtin(__builtin_amdgcn_exp2f)
    return __builtin_amdgcn_exp2f(x);
#else
    return exp2f(x);
#endif
}
__device__ __forceinline__ float frcp(float x) {
#if __has_builtin(__builtin_amdgcn_rcpf)
    return __builtin_amdgcn_rcpf(x);
#else
    return 1.0f / x;
#endif
}
__device__ __forceinline__ v2f vfma(v2f a, v2f b, v2f c) {
    return __builtin_elementwise_fma(a, b, c);
}

// exp(-0.5 (x-m)^2/(softplus(v)+eps)) = exp2(A x^2 + B x + G), k-pair packed.
__device__ __forceinline__ void load_coefs2(
    const float* __restrict__ Mean, const float* __restrict__ Var, int d,
    v2f* Ak2, v2f* Bk2, v2f* Gk2)
{
    const float L2E = 1.4426950408889634f;
#pragma unroll
    for (int kk = 0; kk < Kn / 2; ++kk) {
#pragma unroll
        for (int h = 0; h < 2; ++h) {
            int k = 2 * kk + h;
            float m  = Mean[k * Dn + d];
            float v  = Var[k * Dn + d];
            float sp = logf(1.0f + expf(v));          // softplus
            float c2 = -0.5f * L2E / (sp + EPS);
            if (h == 0) { Ak2[kk].x = c2; Bk2[kk].x = -2.0f * c2 * m; Gk2[kk].x = c2 * m * m; }
            else        { Ak2[kk].y = c2; Bk2[kk].y = -2.0f * c2 * m; Gk2[kk].y = c2 * m * m; }
        }
    }
}

// Pass 1: per-block partials, paired layout [tc][kk][b][d][2]:
//   P0=sum_t tau ; P1=sum_t tau*x ; P3=sum_t tau^3*x^2
template<int TCHT>
__global__ __launch_bounds__(256, 4) void ucb_pass1(
    const float* __restrict__ X,
    const float* __restrict__ Mean, const float* __restrict__ Var,
    float* __restrict__ P0, float* __restrict__ P1, float* __restrict__ P3)
{
    const int d  = threadIdx.x;          // 0..255 (= Dn)
    const int tc = blockIdx.x;           // t-chunk
    const int b  = blockIdx.y;           // batch

    v2f Ak2[4], Bk2[4], Gk2[4];
    load_coefs2(Mean, Var, d, Ak2, Bk2, Gk2);

    v2f s0[4], s1[4], s3[4];
#pragma unroll
    for (int kk = 0; kk < 4; ++kk) {
        s0[kk] = (v2f)(0.f); s1[kk] = (v2f)(0.f); s3[kk] = (v2f)(0.f);
    }

    const float* xp = X + ((size_t)b * Tn + (size_t)tc * TCHT) * Dn + d;
    constexpr int G = TCHT / 4;          // power of 2

    float xc[4];
#pragma unroll
    for (int j = 0; j < 4; ++j) xc[j] = xp[(size_t)j * Dn];

#pragma unroll 1
    for (int g = 0; g < G; ++g) {
        float xn[4];
        const float* xnp = xp + (size_t)((g + 1) & (G - 1)) * 4 * Dn;
#pragma unroll
        for (int j = 0; j < 4; ++j) xn[j] = xnp[(size_t)j * Dn];

#pragma unroll
        for (int j = 0; j < 4; ++j) {
            float xv = xc[j];
            v2f xv2 = (v2f){xv, xv};
            v2f p2[4];
#pragma unroll
            for (int kk = 0; kk < 4; ++kk) {
                v2f arg = vfma(vfma(Ak2[kk], xv2, Bk2[kk]), xv2, Gk2[kk]);
                p2[kk].x = fexp2(arg.x);
                p2[kk].y = fexp2(arg.y);
            }
            v2f sp01 = p2[0] + p2[1];
            v2f sp23 = p2[2] + p2[3];
            v2f spt  = sp01 + sp23;
            float sum = EPS + (spt.x + spt.y);
            float q    = frcp(sum);
            float xq   = xv * q;
            float xxq3 = (xv * xv) * (q * q * q);
            v2f q2v   = (v2f){q, q};
            v2f xq2v  = (v2f){xq, xq};
            v2f xxq3v = (v2f){xxq3, xxq3};
#pragma unroll
            for (int kk = 0; kk < 4; ++kk) {
                v2f pk = p2[kk];
                v2f p3 = pk * pk * pk;
                s0[kk] = vfma(pk, q2v,   s0[kk]);
                s1[kk] = vfma(pk, xq2v,  s1[kk]);
                s3[kk] = vfma(p3, xxq3v, s3[kk]);
            }
        }

#pragma unroll
        for (int j = 0; j < 4; ++j) xc[j] = xn[j];
    }

    // paired epilogue: 8B coalesced stores
#pragma unroll
    for (int kk = 0; kk < 4; ++kk) {
        size_t o = (size_t)tc * KBD + ((size_t)(kk * Bn + b) << 9) + (size_t)d * 2;
        *(v2f*)&P0[o] = s0[kk];
        *(v2f*)&P1[o] = s1[kk];
        *(v2f*)&P3[o] = s3[kk];
    }
}

// Reduce: y==0: Q1 = sum_tc P1 ; y==1: Q3 = sum_tc P3 ;
//         y==2 (x<8): S[kk,d,h] = eps + sum_{b,tc} P0
__global__ __launch_bounds__(256) void ucb_reduce(
    const float* __restrict__ P0, const float* __restrict__ P1,
    const float* __restrict__ P3,
    float* __restrict__ Q, float* __restrict__ S, int ts1)
{
    const int y = blockIdx.y;
    if (y < 2) {
        const size_t idx = (size_t)blockIdx.x * 256 + threadIdx.x;  // over KBD
        const float* p = (y == 0 ? P1 : P3) + idx;
        float a = 0.f;
#pragma unroll 8
        for (int t = 0; t < ts1; ++t)
            a += p[(size_t)t * KBD];
        Q[(size_t)y * KBD + idx] = a;
    } else {
        if (blockIdx.x >= 8) return;
        const int j   = blockIdx.x * 256 + threadIdx.x;   // over KD=2048
        const int kk  = j >> 9;
        const int rem = j & 511;                          // d*2+h
        const size_t base0 = ((size_t)kk << 13) + rem;    // (kk*16)*512 + rem
        float s = EPS;
#pragma unroll 2
        for (int t = 0; t < ts1; ++t) {
            const float* p = P0 + (size_t)t * KBD + base0;
#pragma unroll
            for (int b2 = 0; b2 < Bn; ++b2)
                s += p[(size_t)b2 << 9];
        }
        S[j] = s;
    }
}

// Pass 2: lean v2f prologue (S,Q1,Q3) + output, k-pair packed, reg-pipelined:
//   out = (1/(sum_p+eps)) * sum_k p_k * (Rk*x - Ek)
__global__ __launch_bounds__(256, 4) void ucb_pass2(
    const float* __restrict__ X,
    const float* __restrict__ Mean, const float* __restrict__ Var,
    const float* __restrict__ Q, const float* __restrict__ S,
    float* __restrict__ Out)
{
    const int d  = threadIdx.x;
    const int tc = blockIdx.x;
    const int b  = blockIdx.y;

    v2f Ak2[4], Bk2[4], Gk2[4];
    load_coefs2(Mean, Var, d, Ak2, Bk2, Gk2);

    const float rs = rsqrtf(1.0f + EPS);     // 1/sqrt(pri+eps), pri==1
    v2f Rk2[4], nEk2[4];
#pragma unroll
    for (int kk = 0; kk < 4; ++kk) {
        v2f s2 = *(const v2f*)&S[(kk << 9) + d * 2];         // eps already folded
        v2f iS = (v2f){frcp(s2.x), frcp(s2.y)};
        size_t qidx = ((size_t)(kk * Bn + b) << 9) + (size_t)d * 2;
        v2f a1 = *(const v2f*)&Q[qidx];                      // Q1
        v2f a3 = *(const v2f*)&Q[KBD + qidx];                // Q3
        v2f E  = a1 * iS * (v2f)(1.0f / Tn);
        v2f iS3 = iS * iS * iS;
        v2f V  = a3 * iS3 * (v2f)(1.0f / Tn);
        v2f r  = (v2f){rs * rsqrtf(V.x + EPS), rs * rsqrtf(V.y + EPS)};
        Rk2[kk]  = r;
        nEk2[kk] = -r * E;
    }

    const size_t base = ((size_t)b * Tn + (size_t)tc * TCH2) * Dn + d;
    const float* xp = X + base;
    float* op = Out + base;
    constexpr int G2 = TCH2 / 4;         // power of 2

    float xc[4];
#pragma unroll
    for (int j = 0; j < 4; ++j) xc[j] = xp[(size_t)j * Dn];

#pragma unroll 1
    for (int g = 0; g < G2; ++g) {
        float xn[4];
        const float* xnp = xp + (size_t)((g + 1) & (G2 - 1)) * 4 * Dn;
#pragma unroll
        for (int j = 0; j < 4; ++j) xn[j] = xnp[(size_t)j * Dn];

#pragma unroll
        for (int j = 0; j < 4; ++j) {
            float xv = xc[j];
            v2f xv2 = (v2f){xv, xv};
            v2f p2[4];
#pragma unroll
            for (int kk = 0; kk < 4; ++kk) {
                v2f arg = vfma(vfma(Ak2[kk], xv2, Bk2[kk]), xv2, Gk2[kk]);
                p2[kk].x = fexp2(arg.x);
                p2[kk].y = fexp2(arg.y);
            }
            v2f sp01 = p2[0] + p2[1];
            v2f sp23 = p2[2] + p2[3];
            v2f spt  = sp01 + sp23;
            float sum = EPS + (spt.x + spt.y);
            float inv = frcp(sum);

            v2f acc2 = (v2f)(0.f);
#pragma unroll
            for (int kk = 0; kk < 4; ++kk) {
                v2f inner = vfma(Rk2[kk], xv2, nEk2[kk]);
                acc2 = vfma(p2[kk], inner, acc2);
            }
            float acc = acc2.x + acc2.y;
            op[(size_t)(g * 4 + j) * Dn] = acc * inv;
        }

#pragma unroll
        for (int j = 0; j < 4; ++j) xc[j] = xn[j];
    }
}

extern "C" void kernel_launch(void* const* d_in, const int* in_sizes, int n_in,
                              void* d_out, int out_size, void* d_ws, size_t ws_size,
                              hipStream_t stream)
{
    const float* x    = (const float*)d_in[0];
    const float* mean = (const float*)d_in[1];
    const float* var  = (const float*)d_in[2];
    // d_in[3] (prior): softmax over singleton axis == 1 -> compile-time rsqrt(1+eps)

    // ws: P0,P1,P3 (3*ts1*KBD) + Q (2*KBD) + S (KD).  ts1=32 (validated optimum).
    int ts1 = 32;
    while (ts1 > 16) {
        size_t need = (3 * (size_t)ts1 * KBD + 2 * KBD + KD) * sizeof(float);
        if (need <= ws_size) break;
        ts1 >>= 1;
    }

    float* P0 = (float*)d_ws;                // ts1*KBD each
    float* P1 = P0 + (size_t)ts1 * KBD;
    float* P3 = P1 + (size_t)ts1 * KBD;
    float* Q  = P3 + (size_t)ts1 * KBD;      // 2*KBD (Q1,Q3)
    float* S  = Q + 2 * KBD;                 // KD

    dim3 g1(ts1, Bn), blk(256);
    const int tcht = Tn / ts1;               // 64 or 128
    if (tcht == 64) {
        ucb_pass1<64><<<g1, blk, 0, stream>>>(x, mean, var, P0, P1, P3);
    } else {
        ucb_pass1<128><<<g1, blk, 0, stream>>>(x, mean, var, P0, P1, P3);
    }

    ucb_reduce<<<dim3(KBD / 256, 3), dim3(256), 0, stream>>>(P0, P1, P3, Q, S, ts1);

    ucb_pass2<<<dim3(TS2, Bn), dim3(256), 0, stream>>>(x, mean, var, Q, S, (float*)d_out);
}

// Round 18
// 48.558 us; speedup vs baseline: 1.2124x; 1.2124x over previous
//
#include <hip/hip_runtime.h>

#define EPS 1e-3f
#define Bn 16
#define Tn 2048
#define Dn 256
#define Kn 8

#define TS2 32           // t-chunks per batch row for pass2
#define TCH2 (Tn / TS2)  // 64

#define KBD ((size_t)Kn * Bn * Dn)   // 32768

typedef float v2f __attribute__((ext_vector_type(2)));

__device__ __forceinline__ float fexp2(float x) {
#if __has_builtin(__builtin_amdgcn_exp2f)
    return __builtin_amdgcn_exp2f(x);
#else
    return exp2f(x);
#endif
}
__device__ __forceinline__ float frcp(float x) {
#if __has_builtin(__builtin_amdgcn_rcpf)
    return __builtin_amdgcn_rcpf(x);
#else
    return 1.0f / x;
#endif
}
__device__ __forceinline__ v2f vfma(v2f a, v2f b, v2f c) {
    return __builtin_elementwise_fma(a, b, c);
}

// exp(-0.5 (x-m)^2/(softplus(v)+eps)) = exp2(A x^2 + B x + G), k-pair packed.
__device__ __forceinline__ void load_coefs2(
    const float* __restrict__ Mean, const float* __restrict__ Var, int d,
    v2f* Ak2, v2f* Bk2, v2f* Gk2)
{
    const float L2E = 1.4426950408889634f;
#pragma unroll
    for (int kk = 0; kk < Kn / 2; ++kk) {
#pragma unroll
        for (int h = 0; h < 2; ++h) {
            int k = 2 * kk + h;
            float m  = Mean[k * Dn + d];
            float v  = Var[k * Dn + d];
            float sp = logf(1.0f + expf(v));          // softplus
            float c2 = -0.5f * L2E / (sp + EPS);
            if (h == 0) { Ak2[kk].x = c2; Bk2[kk].x = -2.0f * c2 * m; Gk2[kk].x = c2 * m * m; }
            else        { Ak2[kk].y = c2; Bk2[kk].y = -2.0f * c2 * m; Gk2[kk].y = c2 * m * m; }
        }
    }
}

// Pass 1: per-block partials (no atomics), k-pair packed, reg-pipelined loads:
//   P0[tc,k,b,d]=sum_t tau ; P1=sum_t tau*x ; P3=sum_t tau^3*x^2
template<int TCHT>
__global__ __launch_bounds__(256, 4) void ucb_pass1(
    const float* __restrict__ X,
    const float* __restrict__ Mean, const float* __restrict__ Var,
    float* __restrict__ P0, float* __restrict__ P1, float* __restrict__ P3)
{
    const int d  = threadIdx.x;          // 0..255 (= Dn)
    const int tc = blockIdx.x;           // t-chunk
    const int b  = blockIdx.y;           // batch

    v2f Ak2[4], Bk2[4], Gk2[4];
    load_coefs2(Mean, Var, d, Ak2, Bk2, Gk2);

    v2f s0[4], s1[4], s3[4];
#pragma unroll
    for (int kk = 0; kk < 4; ++kk) {
        s0[kk] = (v2f)(0.f); s1[kk] = (v2f)(0.f); s3[kk] = (v2f)(0.f);
    }

    const float* xp = X + ((size_t)b * Tn + (size_t)tc * TCHT) * Dn + d;
    constexpr int G = TCHT / 4;          // groups of 4 (G is a power of 2)

    float xc[4];
#pragma unroll
    for (int j = 0; j < 4; ++j) xc[j] = xp[(size_t)j * Dn];

#pragma unroll 1
    for (int g = 0; g < G; ++g) {
        // prefetch next group's 4 x's (wraps to group 0 on the last iter --
        // harmless redundant loads, keeps the loop branch-free)
        float xn[4];
        const float* xnp = xp + (size_t)((g + 1) & (G - 1)) * 4 * Dn;
#pragma unroll
        for (int j = 0; j < 4; ++j) xn[j] = xnp[(size_t)j * Dn];

#pragma unroll
        for (int j = 0; j < 4; ++j) {
            float xv = xc[j];
            v2f xv2 = (v2f){xv, xv};
            v2f p2[4];
#pragma unroll
            for (int kk = 0; kk < 4; ++kk) {
                v2f arg = vfma(vfma(Ak2[kk], xv2, Bk2[kk]), xv2, Gk2[kk]);
                p2[kk].x = fexp2(arg.x);
                p2[kk].y = fexp2(arg.y);
            }
            v2f sp01 = p2[0] + p2[1];
            v2f sp23 = p2[2] + p2[3];
            v2f spt  = sp01 + sp23;
            float sum = EPS + (spt.x + spt.y);
            float q    = frcp(sum);
            float xq   = xv * q;
            float xxq3 = (xv * xv) * (q * q * q);
            v2f q2v   = (v2f){q, q};
            v2f xq2v  = (v2f){xq, xq};
            v2f xxq3v = (v2f){xxq3, xxq3};
#pragma unroll
            for (int kk = 0; kk < 4; ++kk) {
                v2f pk = p2[kk];
                v2f p3 = pk * pk * pk;
                s0[kk] = vfma(pk, q2v,   s0[kk]);
                s1[kk] = vfma(pk, xq2v,  s1[kk]);
                s3[kk] = vfma(p3, xxq3v, s3[kk]);
            }
        }

#pragma unroll
        for (int j = 0; j < 4; ++j) xc[j] = xn[j];
    }

#pragma unroll
    for (int kk = 0; kk < 4; ++kk) {
#pragma unroll
        for (int h = 0; h < 2; ++h) {
            int k = 2 * kk + h;
            size_t o = (size_t)tc * KBD + ((size_t)(k * Bn + b) << 8) + d;
            P0[o] = h ? s0[kk].y : s0[kk].x;
            P1[o] = h ? s1[kk].y : s1[kk].x;
            P3[o] = h ? s3[kk].y : s3[kk].x;
        }
    }
}

// Reduce: Q[arr][idx] = sum_tc P[arr][tc][idx]
__global__ __launch_bounds__(256) void ucb_reduce(
    const float* __restrict__ P, float* __restrict__ Q, int ts1)
{
    const size_t idx = (size_t)blockIdx.x * 256 + threadIdx.x;  // over KBD
    const int arr = blockIdx.y;      // 0..2

    const float* p = P + (size_t)arr * ts1 * KBD + idx;
    float a = 0.f;
#pragma unroll 8
    for (int t = 0; t < ts1; ++t)
        a += p[(size_t)t * KBD];
    Q[(size_t)arr * KBD + idx] = a;
}

// Pass 2: inline mid (S,R,E from Q) + output, k-pair packed, reg-pipelined:
//   out = (1/(sum_p+eps)) * sum_k p_k * (Rk*x - Ek)
__global__ __launch_bounds__(256, 4) void ucb_pass2(
    const float* __restrict__ X,
    const float* __restrict__ Mean, const float* __restrict__ Var,
    const float* __restrict__ Q,
    float* __restrict__ Out)
{
    const int d  = threadIdx.x;
    const int tc = blockIdx.x;
    const int b  = blockIdx.y;

    v2f Ak2[4], Bk2[4], Gk2[4];
    load_coefs2(Mean, Var, d, Ak2, Bk2, Gk2);

    // inline "mid": S[k,d] = eps + sum_b Q0 ; E,V,R from Q1,Q3; pack k-pairs
    const float rs = rsqrtf(1.0f + EPS);     // 1/sqrt(pri+eps), pri==1
    v2f Rk2[4], nEk2[4];
#pragma unroll
    for (int kk = 0; kk < 4; ++kk) {
#pragma unroll
        for (int h = 0; h < 2; ++h) {
            int k = 2 * kk + h;
            const float* q0 = Q + ((size_t)k << 12) + d;   // Q0[k,*,d]
            float s = EPS;
#pragma unroll
            for (int b2 = 0; b2 < Bn; ++b2)
                s += q0[(size_t)b2 << 8];
            float iS = frcp(s);

            size_t idx = ((size_t)(k * Bn + b) << 8) + d;
            float a1 = Q[KBD + idx];
            float a3 = Q[2 * KBD + idx];
            float E  = a1 * iS * (1.0f / Tn);
            float V  = a3 * (iS * iS * iS) * (1.0f / Tn);
            float r  = rs * rsqrtf(V + EPS);
            if (h == 0) { Rk2[kk].x = r; nEk2[kk].x = -r * E; }
            else        { Rk2[kk].y = r; nEk2[kk].y = -r * E; }
        }
    }

    const size_t base = ((size_t)b * Tn + (size_t)tc * TCH2) * Dn + d;
    const float* xp = X + base;
    float* op = Out + base;
    constexpr int G2 = TCH2 / 4;         // power of 2

    float xc[4];
#pragma unroll
    for (int j = 0; j < 4; ++j) xc[j] = xp[(size_t)j * Dn];

#pragma unroll 1
    for (int g = 0; g < G2; ++g) {
        float xn[4];
        const float* xnp = xp + (size_t)((g + 1) & (G2 - 1)) * 4 * Dn;
#pragma unroll
        for (int j = 0; j < 4; ++j) xn[j] = xnp[(size_t)j * Dn];

#pragma unroll
        for (int j = 0; j < 4; ++j) {
            float xv = xc[j];
            v2f xv2 = (v2f){xv, xv};
            v2f p2[4];
#pragma unroll
            for (int kk = 0; kk < 4; ++kk) {
                v2f arg = vfma(vfma(Ak2[kk], xv2, Bk2[kk]), xv2, Gk2[kk]);
                p2[kk].x = fexp2(arg.x);
                p2[kk].y = fexp2(arg.y);
            }
            v2f sp01 = p2[0] + p2[1];
            v2f sp23 = p2[2] + p2[3];
            v2f spt  = sp01 + sp23;
            float sum = EPS + (spt.x + spt.y);
            float inv = frcp(sum);

            v2f acc2 = (v2f)(0.f);
#pragma unroll
            for (int kk = 0; kk < 4; ++kk) {
                v2f inner = vfma(Rk2[kk], xv2, nEk2[kk]);
                acc2 = vfma(p2[kk], inner, acc2);
            }
            float acc = acc2.x + acc2.y;
            op[(size_t)(g * 4 + j) * Dn] = acc * inv;
        }

#pragma unroll
        for (int j = 0; j < 4; ++j) xc[j] = xn[j];
    }
}

extern "C" void kernel_launch(void* const* d_in, const int* in_sizes, int n_in,
                              void* d_out, int out_size, void* d_ws, size_t ws_size,
                              hipStream_t stream)
{
    const float* x    = (const float*)d_in[0];
    const float* mean = (const float*)d_in[1];
    const float* var  = (const float*)d_in[2];
    // d_in[3] (prior): softmax over singleton axis == 1 -> compile-time rsqrt(1+eps)

    // ws: P (3*ts1*KBD) + Q (3*KBD).  ts1=32 (validated optimum).
    int ts1 = 32;
    while (ts1 > 16) {
        size_t need = (3 * (size_t)ts1 * KBD + 3 * KBD) * sizeof(float);
        if (need <= ws_size) break;
        ts1 >>= 1;
    }

    float* P = (float*)d_ws;                 // 3*ts1*KBD
    float* Q = P + 3 * (size_t)ts1 * KBD;    // 3*KBD

    dim3 g1(ts1, Bn), blk(256);
    const int tcht = Tn / ts1;               // 64 or 128
    if (tcht == 64) {
        ucb_pass1<64><<<g1, blk, 0, stream>>>(x, mean, var,
            P, P + (size_t)ts1 * KBD, P + 2 * (size_t)ts1 * KBD);
    } else {
        ucb_pass1<128><<<g1, blk, 0, stream>>>(x, mean, var,
            P, P + (size_t)ts1 * KBD, P + 2 * (size_t)ts1 * KBD);
    }

    ucb_reduce<<<dim3(KBD / 256, 3), dim3(256), 0, stream>>>(P, Q, ts1);

    ucb_pass2<<<dim3(TS2, Bn), dim3(256), 0, stream>>>(x, mean, var, Q, (float*)d_out);
}